// Round 1
// baseline (2520.229 us; speedup 1.0000x reference)
//
#include <hip/hip_runtime.h>
#include <math.h>

// B=4, O=8, C=256, HID=128, H=W=64, STEPS=2
// Algebraic decomposition (conv is linear):
//   enc:  relu(conv(feats, Wf) + conv(mask, Wm) + b)         -- Wf part shared over O
//   gcn:  relu(conv(s, W1-W2) + [conv(Sum_o s, W2) + b])     -- Sum part shared over O
//   ro :  sigmoid(conv(feats, Wa) + conv(s, Wb) + b)         -- Wa part shared over O
// Total FLOPs ~9.7e10 vs 3.1e11 naive.

#define HW 4096
constexpr int TS = 16;  // spatial tile (16x16)
constexpr int CT = 16;  // cout tile
constexpr int CC = 16;  // cin chunk

// Direct tiled conv3x3, SAME padding, optional weight-subtract (W1-W2),
// optional bias, optional per-batch additive input, optional relu.
__global__ __launch_bounds__(256) void conv3x3_tiled(
    const float* __restrict__ x, int x_img_stride,
    const float* __restrict__ w, int w_cin_total, int w_cin_off, int w_sub,
    int cin,
    const float* __restrict__ bias,
    const float* __restrict__ addin, int addin_shift,
    float* __restrict__ y, int cout_total, int relu)
{
    __shared__ float xs[CC][18][19];   // +1 pad to break bank strides
    __shared__ float ws[CC][9][CT];    // [ci][k][co] -> float4 over co

    const int img = blockIdx.z;
    const int co0 = blockIdx.y * CT;
    const int tile = blockIdx.x;
    const int ty0 = (tile >> 2) * TS;
    const int tx0 = (tile & 3) * TS;
    const int tid = threadIdx.x;
    const int cg = tid >> 6;         // 4 cout-groups of 4
    const int lane = tid & 63;
    const int by = lane >> 3, bx = lane & 7;
    const int py0 = by * 2, px0 = bx * 2;   // 2x2 pixel block per thread

    float acc[4][4];
#pragma unroll
    for (int c = 0; c < 4; ++c)
#pragma unroll
        for (int p = 0; p < 4; ++p) acc[c][p] = 0.f;

    const float* ximg = x + (size_t)img * x_img_stride;

    for (int ci0 = 0; ci0 < cin; ci0 += CC) {
        const int chunk = min(CC, cin - ci0);
        __syncthreads();
        // stage input tile (with halo, zero-padded)
        for (int idx = tid; idx < chunk * 324; idx += 256) {
            int ci = idx / 324;
            int rem = idx - ci * 324;
            int yy = rem / 18;
            int xx = rem - yy * 18;
            int gy = ty0 + yy - 1, gx = tx0 + xx - 1;
            float v = 0.f;
            if ((unsigned)gy < 64u && (unsigned)gx < 64u)
                v = ximg[(ci0 + ci) * HW + gy * 64 + gx];
            xs[ci][yy][xx] = v;
        }
        // stage weights (optionally W1 - W2 with W2 at cin offset +128)
        for (int idx = tid; idx < chunk * 9 * CT; idx += 256) {
            int ci = idx / (9 * CT);
            int rem = idx - ci * 9 * CT;
            int k = rem >> 4;
            int co = rem & 15;
            const float* wp = w + ((size_t)(co0 + co) * w_cin_total + (w_cin_off + ci0 + ci)) * 9 + k;
            float v = wp[0];
            if (w_sub) v -= wp[128 * 9];
            ws[ci][k][co] = v;
        }
        __syncthreads();

        for (int ci = 0; ci < chunk; ++ci) {
            float xv[4][4];
#pragma unroll
            for (int yy = 0; yy < 4; ++yy)
#pragma unroll
                for (int xx = 0; xx < 4; ++xx)
                    xv[yy][xx] = xs[ci][py0 + yy][px0 + xx];
#pragma unroll
            for (int dy = 0; dy < 3; ++dy)
#pragma unroll
                for (int dx = 0; dx < 3; ++dx) {
                    const float4 w4 = *(const float4*)&ws[ci][dy * 3 + dx][cg * 4];
                    const float wv[4] = {w4.x, w4.y, w4.z, w4.w};
#pragma unroll
                    for (int c = 0; c < 4; ++c)
#pragma unroll
                        for (int py = 0; py < 2; ++py)
#pragma unroll
                            for (int px = 0; px < 2; ++px)
                                acc[c][py * 2 + px] =
                                    fmaf(wv[c], xv[py + dy][px + dx], acc[c][py * 2 + px]);
                }
        }
    }

    const size_t ybase = (size_t)img * cout_total * HW;
    const float* aimg = addin ? addin + (size_t)(img >> addin_shift) * cout_total * HW : nullptr;
#pragma unroll
    for (int c = 0; c < 4; ++c) {
        const int co = co0 + cg * 4 + c;
        const float bv = bias ? bias[co] : 0.f;
#pragma unroll
        for (int py = 0; py < 2; ++py)
#pragma unroll
            for (int px = 0; px < 2; ++px) {
                int gy = ty0 + py0 + py, gx = tx0 + px0 + px;
                float v = acc[c][py * 2 + px] + bv;
                if (aimg) v += aimg[co * HW + gy * 64 + gx];
                if (relu) v = fmaxf(v, 0.f);
                y[ybase + co * HW + gy * 64 + gx] = v;
            }
    }
}

// Sum over the 8 objects: states [32,128,4096] -> [4,128,4096]
__global__ __launch_bounds__(256) void sum8_kernel(const float* __restrict__ s,
                                                   float* __restrict__ out)
{
    int idx = blockIdx.x * 256 + threadIdx.x;   // 4*128*4096
    int b = idx >> 19;                          // 524288 per batch
    int rem = idx & 524287;
    const float* p = s + (size_t)b * 8 * 524288 + rem;
    float v = 0.f;
#pragma unroll
    for (int o = 0; o < 8; ++o) v += p[(size_t)o * 524288];
    out[idx] = v;
}

// Readout shared part: yro[b,p] = conv(feats[b], ro_w[:, :256]) + ro_b
__global__ __launch_bounds__(256) void ro_shared_kernel(const float* __restrict__ feats,
                                                        const float* __restrict__ ro_w,
                                                        const float* __restrict__ ro_b,
                                                        float* __restrict__ yro)
{
    int idx = blockIdx.x * 256 + threadIdx.x;   // 4*4096
    int b = idx >> 12;
    int p = idx & 4095;
    int yy = p >> 6, xx = p & 63;
    float acc = ro_b[0];
    const float* xb = feats + (size_t)b * 256 * HW;
    for (int ci = 0; ci < 256; ++ci) {
        const float* xp = xb + ci * HW;
        const float* wp = ro_w + ci * 9;
#pragma unroll
        for (int dy = 0; dy < 3; ++dy) {
            int gy = yy + dy - 1;
            if ((unsigned)gy >= 64u) continue;
#pragma unroll
            for (int dx = 0; dx < 3; ++dx) {
                int gx = xx + dx - 1;
                if ((unsigned)gx >= 64u) continue;
                acc = fmaf(wp[dy * 3 + dx], xp[gy * 64 + gx], acc);
            }
        }
    }
    yro[idx] = acc;
}

// Readout object part: out[n,p] = sigmoid(yro[b,p] + conv(states[n], ro_w[:,256:384]))
__global__ __launch_bounds__(256) void ro_obj_kernel(const float* __restrict__ states,
                                                     const float* __restrict__ ro_w,
                                                     const float* __restrict__ yro,
                                                     float* __restrict__ out)
{
    int idx = blockIdx.x * 256 + threadIdx.x;   // 32*4096
    int n = idx >> 12;
    int b = n >> 3;
    int p = idx & 4095;
    int yy = p >> 6, xx = p & 63;
    float acc = yro[b * HW + p];
    const float* xb = states + (size_t)n * 128 * HW;
    const float* wb = ro_w + 256 * 9;
    for (int ci = 0; ci < 128; ++ci) {
        const float* xp = xb + ci * HW;
        const float* wp = wb + ci * 9;
#pragma unroll
        for (int dy = 0; dy < 3; ++dy) {
            int gy = yy + dy - 1;
            if ((unsigned)gy >= 64u) continue;
#pragma unroll
            for (int dx = 0; dx < 3; ++dx) {
                int gx = xx + dx - 1;
                if ((unsigned)gx >= 64u) continue;
                acc = fmaf(wp[dy * 3 + dx], xp[gy * 64 + gx], acc);
            }
        }
    }
    out[idx] = 1.f / (1.f + expf(-acc));
}

extern "C" void kernel_launch(void* const* d_in, const int* in_sizes, int n_in,
                              void* d_out, int out_size, void* d_ws, size_t ws_size,
                              hipStream_t stream)
{
    const float* feats = (const float*)d_in[0];   // [4,256,64,64]
    const float* masks = (const float*)d_in[1];   // [4,8,64,64]
    // d_in[2] valid indices (all true), d_in[3] prev states (unused)
    const float* enc_w = (const float*)d_in[4];   // [128,257,3,3]
    const float* enc_b = (const float*)d_in[5];
    const float* gcn_w = (const float*)d_in[6];   // [128,256,3,3]
    const float* gcn_b = (const float*)d_in[7];
    const float* ro_w  = (const float*)d_in[8];   // [1,384,3,3]
    const float* ro_b  = (const float*)d_in[9];
    float* out = (float*)d_out;                   // [4,8,64,64]

    // workspace layout (floats): ~144 MB total
    float* S0 = (float*)d_ws;                     // [32,128,4096]
    float* S1 = S0 + 16777216;                    // [32,128,4096]
    float* U1 = S1 + 16777216;                    // [4,128,4096] (Yenc_shared / Sum)
    float* U2 = U1 + 2097152;                     // [4,128,4096] (Ygcn_shared)
    float* YR = U2 + 2097152;                     // [4,4096]

    dim3 blk(256);

    // encoder: shared feats conv -> U1 ; per-object mask conv + relu -> S0
    conv3x3_tiled<<<dim3(16, 8, 4), blk, 0, stream>>>(
        feats, 256 * HW, enc_w, 257, 0, 0, 256, enc_b, nullptr, 0, U1, 128, 0);
    conv3x3_tiled<<<dim3(16, 8, 32), blk, 0, stream>>>(
        masks, HW, enc_w, 257, 256, 0, 1, nullptr, U1, 3, S0, 128, 1);

    // 2 message-passing steps
    for (int step = 0; step < 2; ++step) {
        const float* sin = step ? S1 : S0;
        float* sout = step ? S0 : S1;
        sum8_kernel<<<8192, blk, 0, stream>>>(sin, U1);
        conv3x3_tiled<<<dim3(16, 8, 4), blk, 0, stream>>>(
            U1, 128 * HW, gcn_w, 256, 128, 0, 128, gcn_b, nullptr, 0, U2, 128, 0);
        conv3x3_tiled<<<dim3(16, 8, 32), blk, 0, stream>>>(
            sin, 128 * HW, gcn_w, 256, 0, /*w_sub=*/1, 128, nullptr, U2, 3, sout, 128, 1);
    }

    // readout (final states are in S0)
    ro_shared_kernel<<<64, blk, 0, stream>>>(feats, ro_w, ro_b, YR);
    ro_obj_kernel<<<512, blk, 0, stream>>>(S0, ro_w, YR, out);
}

// Round 3
// 520.531 us; speedup vs baseline: 4.8417x; 4.8417x over previous
//
#include <hip/hip_runtime.h>
#include <math.h>

// B=4, O=8, C=256, HID=128, H=W=64, STEPS=2
// fp16 MFMA implicit-GEMM conv. Decomposition (conv is linear):
//   enc:  relu(conv(feats,Wf) [shared/4img, fp32 out] + conv(mask,Wm) + b)
//   gcn:  relu(conv(s, W1-W2) + [conv(Sum_o s, W2) + b] [shared/4img, fp32 out])
//   ro :  sigmoid(conv(feats,Wa) [shared] + conv(s,Wb) + b)
// Activations fp16 HWC: x[img][px][ci].  Weights pre-packed fp16
// [tap][cout][cin] so MFMA A-fragments are contiguous 16B global loads.
// Shared terms U1/U2 kept fp32 to avoid rounding the dominant addend.

typedef unsigned short ushort_t;
typedef _Float16 f16x8 __attribute__((ext_vector_type(8)));
typedef float f32x4 __attribute__((ext_vector_type(4)));

__device__ __forceinline__ ushort_t f2h(float f) {
    _Float16 h = (_Float16)f;           // v_cvt_f16_f32, RNE
    return *(ushort_t*)&h;
}
__device__ __forceinline__ float h2f(ushort_t u) {
    _Float16 h = *(_Float16*)&u;
    return (float)h;
}

// ---- weight packing: WencF[9][128][256], WgcnS[9][128][128], WgcnD[9][128][128]
__global__ __launch_bounds__(256) void prep_weights(
    const float* __restrict__ enc_w, const float* __restrict__ gcn_w,
    ushort_t* __restrict__ WencF, ushort_t* __restrict__ WgcnS, ushort_t* __restrict__ WgcnD)
{
    int i = blockIdx.x * 256 + threadIdx.x;
    if (i < 294912) {                       // enc feats part: [t][co][ci<256]
        int t = i / 32768; int r = i & 32767; int co = r >> 8; int ci = r & 255;
        WencF[i] = f2h(enc_w[(co * 257 + ci) * 9 + t]);
    } else if (i < 442368) {                // gcn shared part W2
        int j = i - 294912; int t = j / 16384; int r = j & 16383; int co = r >> 7; int ci = r & 127;
        WgcnS[j] = f2h(gcn_w[(co * 256 + 128 + ci) * 9 + t]);
    } else if (i < 589824) {                // gcn diff W1-W2
        int j = i - 442368; int t = j / 16384; int r = j & 16383; int co = r >> 7; int ci = r & 127;
        WgcnD[j] = f2h(gcn_w[(co * 256 + ci) * 9 + t] - gcn_w[(co * 256 + 128 + ci) * 9 + t]);
    }
}

// ---- feats fp32 CHW -> fp16 HWC  [4][4096][256]
__global__ __launch_bounds__(256) void feats_to_hwc(const float* __restrict__ feats,
                                                    ushort_t* __restrict__ featsT)
{
    __shared__ float tile[64][65];
    int img = blockIdx.z, ct = blockIdx.y, pt = blockIdx.x;
    int t = threadIdx.x;
    int px_l = t & 63;
    const float* src = feats + ((size_t)img * 256 + ct * 64) * 4096 + pt * 64;
#pragma unroll
    for (int j = 0; j < 16; ++j) {
        int ci_l = (t >> 6) + j * 4;
        tile[px_l][ci_l] = src[(size_t)ci_l * 4096 + px_l];
    }
    __syncthreads();
    int px = t >> 2;
#pragma unroll
    for (int j = 0; j < 2; ++j) {
        int c8 = ((t & 3) + j * 4) * 8;
        uint4 v; ushort_t* pv = (ushort_t*)&v;
#pragma unroll
        for (int k = 0; k < 8; ++k) pv[k] = f2h(tile[px][c8 + k]);
        *(uint4*)(featsT + ((size_t)img * 4096 + pt * 64 + px) * 256 + ct * 64 + c8) = v;
    }
}

// ---- main MFMA conv: x fp16 HWC [img][4096][cin] -> out fp16 (or fp32) HWC [img][4096][128]
// block = one row (64 px) x 128 couts, 4 waves; wave: 2 cout-tiles x 4 px-tiles.
__global__ __launch_bounds__(256, 4) void conv_mfma(
    const ushort_t* __restrict__ x, int cin,
    const ushort_t* __restrict__ W,           // [9][128][cin] fp16
    const float* __restrict__ bias,           // [128] or null
    const float* __restrict__ addin32,        // fp32 HWC [?][4096][128] or null
    int addin_shift,
    ushort_t* __restrict__ out,               // fp16 out (used if out32==null)
    float* __restrict__ out32, int relu)
{
    __shared__ uint4 raw4[1088];              // 17408 B: xs [3][66][40] fp16 / outF [64][68] f32
    ushort_t* xs = (ushort_t*)raw4;
    float* outF = (float*)raw4;

    const int row = blockIdx.x, img = blockIdx.y;
    const int tid = threadIdx.x;
    const int w = tid >> 6, lane = tid & 63, lq = lane >> 4, lr = lane & 15;
    const ushort_t* ximg = x + (size_t)img * 4096 * cin;

    f32x4 acc[2][4];
#pragma unroll
    for (int a = 0; a < 2; ++a)
#pragma unroll
        for (int p = 0; p < 4; ++p) acc[a][p] = (f32x4){0.f, 0.f, 0.f, 0.f};

    for (int ci0 = 0; ci0 < cin; ci0 += 32) {
        __syncthreads();
        // stage 3 rows x 66 cols x 32 ci (fp16) as 16B chunks
        for (int i = tid; i < 792; i += 256) {
            int r = i / 264; int rem = i - r * 264; int c = rem >> 2; int s = rem & 3;
            int gy = row - 1 + r, gx = c - 1;
            uint4 v = make_uint4(0, 0, 0, 0);
            if ((unsigned)gy < 64u && (unsigned)gx < 64u)
                v = *(const uint4*)(ximg + (size_t)(gy * 64 + gx) * cin + ci0 + s * 8);
            *(uint4*)(xs + (r * 66 + c) * 40 + s * 8) = v;
        }
        __syncthreads();
        const ushort_t* Wc = W + ci0 + lq * 8;
        for (int t = 0; t < 9; ++t) {
            int dy = t / 3, dx = t - dy * 3;
            f16x8 a0 = *(const f16x8*)(Wc + (size_t)(t * 128 + w * 32 + lr) * cin);
            f16x8 a1 = *(const f16x8*)(Wc + (size_t)(t * 128 + w * 32 + 16 + lr) * cin);
            const ushort_t* bb = xs + (dy * 66 + dx + lr) * 40 + lq * 8;
#pragma unroll
            for (int p = 0; p < 4; ++p) {
                f16x8 b = *(const f16x8*)(bb + p * 640);   // p*16*40
                acc[0][p] = __builtin_amdgcn_mfma_f32_16x16x32_f16(a0, b, acc[0][p], 0, 0, 0);
                acc[1][p] = __builtin_amdgcn_mfma_f32_16x16x32_f16(a1, b, acc[1][p], 0, 0, 0);
            }
        }
    }

    // epilogue: fp32 LDS transpose (half of couts at a time), fused bias/addin/relu
    const float* add_px = addin32
        ? addin32 + ((size_t)(img >> addin_shift) * 4096 + row * 64) * 128 : (const float*)0;
    ushort_t* obase = out ? out + ((size_t)img * 4096 + row * 64) * 128 : (ushort_t*)0;
    float* obase32 = out32 ? out32 + ((size_t)img * 4096 + row * 64) * 128 : (float*)0;

    for (int h = 0; h < 2; ++h) {
        __syncthreads();
        if ((w >> 1) == h) {
            int wl = w & 1;
#pragma unroll
            for (int a = 0; a < 2; ++a)
#pragma unroll
                for (int p = 0; p < 4; ++p) {
                    int co_l = wl * 32 + a * 16 + lq * 4;
                    int px = p * 16 + lr;
                    *(f32x4*)(outF + px * 68 + co_l) = acc[a][p];
                }
        }
        __syncthreads();
        for (int i = tid; i < 512; i += 256) {
            int px = i >> 3, c8l = (i & 7) << 3;
            int c8 = h * 64 + c8l;
            f32x4 v0 = *(f32x4*)(outF + px * 68 + c8l);
            f32x4 v1 = *(f32x4*)(outF + px * 68 + c8l + 4);
            float v[8] = {v0[0], v0[1], v0[2], v0[3], v1[0], v1[1], v1[2], v1[3]};
            if (bias) {
#pragma unroll
                for (int k = 0; k < 8; ++k) v[k] += bias[c8 + k];
            }
            if (add_px) {
                float4 a0 = *(const float4*)(add_px + px * 128 + c8);
                float4 a1 = *(const float4*)(add_px + px * 128 + c8 + 4);
                v[0] += a0.x; v[1] += a0.y; v[2] += a0.z; v[3] += a0.w;
                v[4] += a1.x; v[5] += a1.y; v[6] += a1.z; v[7] += a1.w;
            }
            if (relu) {
#pragma unroll
                for (int k = 0; k < 8; ++k) v[k] = fmaxf(v[k], 0.f);
            }
            if (obase32) {
                *(float4*)(obase32 + px * 128 + c8) = make_float4(v[0], v[1], v[2], v[3]);
                *(float4*)(obase32 + px * 128 + c8 + 4) = make_float4(v[4], v[5], v[6], v[7]);
            } else {
                uint4 sv; ushort_t* sp = (ushort_t*)&sv;
#pragma unroll
                for (int k = 0; k < 8; ++k) sp[k] = f2h(v[k]);
                *(uint4*)(obase + px * 128 + c8) = sv;
            }
        }
    }
}

// ---- sum over 8 objects: S[32][4096][128] -> U[4][4096][128] (fp16, fp32 accum)
__global__ __launch_bounds__(256) void sum8_hwc(const ushort_t* __restrict__ s,
                                                ushort_t* __restrict__ u)
{
    int i = blockIdx.x * 256 + threadIdx.x;     // 4 * 65536 chunks of 8
    int b = i >> 16; int r = i & 65535;
    const ushort_t* p = s + (size_t)b * 8 * 524288 + (size_t)r * 8;
    float v[8] = {0, 0, 0, 0, 0, 0, 0, 0};
#pragma unroll
    for (int o = 0; o < 8; ++o) {
        uint4 xv = *(const uint4*)(p + (size_t)o * 524288);
        const ushort_t* xp = (const ushort_t*)&xv;
#pragma unroll
        for (int k = 0; k < 8; ++k) v[k] += h2f(xp[k]);
    }
    uint4 sv; ushort_t* sp = (ushort_t*)&sv;
#pragma unroll
    for (int k = 0; k < 8; ++k) sp[k] = f2h(v[k]);
    *(uint4*)(u + (size_t)b * 524288 + (size_t)r * 8) = sv;
}

// ---- encoder per-object part: S0 = relu(U1[b] (fp32) + conv3x3(mask_n, Wm))
__global__ __launch_bounds__(256) void enc_obj(
    const float* __restrict__ masks, const float* __restrict__ enc_w,
    const float* __restrict__ U1, ushort_t* __restrict__ S0)
{
    int i = blockIdx.x * 256 + threadIdx.x;     // n(5)|px(12)|cg(4)
    int cg = i & 15, px = (i >> 4) & 4095, n = i >> 16;
    int y = px >> 6, xx = px & 63;
    const float* m = masks + (size_t)n * 4096;
    float mt[9];
#pragma unroll
    for (int dy = 0; dy < 3; ++dy)
#pragma unroll
        for (int dx = 0; dx < 3; ++dx) {
            int gy = y + dy - 1, gx = xx + dx - 1;
            mt[dy * 3 + dx] = ((unsigned)gy < 64u && (unsigned)gx < 64u) ? m[gy * 64 + gx] : 0.f;
        }
    const float* ub = U1 + ((size_t)(n >> 3) * 4096 + px) * 128 + cg * 8;
    float4 u0 = *(const float4*)ub;
    float4 u1 = *(const float4*)(ub + 4);
    float uv[8] = {u0.x, u0.y, u0.z, u0.w, u1.x, u1.y, u1.z, u1.w};
    uint4 sv; ushort_t* sp = (ushort_t*)&sv;
#pragma unroll
    for (int k = 0; k < 8; ++k) {
        int co = cg * 8 + k;
        const float* wp = enc_w + (size_t)(co * 257 + 256) * 9;
        float acc = uv[k];
#pragma unroll
        for (int t = 0; t < 9; ++t) acc = fmaf(mt[t], wp[t], acc);
        sp[k] = f2h(fmaxf(acc, 0.f));
    }
    *(uint4*)(S0 + ((size_t)n * 4096 + px) * 128 + cg * 8) = sv;
}

// ---- readout shared part (fp32 feats CHW), split over ci-chunks + atomicAdd
__global__ __launch_bounds__(256) void ro_shared(const float* __restrict__ feats,
                                                 const float* __restrict__ ro_w,
                                                 float* __restrict__ YR)
{
    int i = blockIdx.x * 256 + threadIdx.x;     // b(2)|chunk(3)|px(12)
    int px = i & 4095, chunk = (i >> 12) & 7, b = i >> 15;
    int y = px >> 6, xx = px & 63;
    const float* xb = feats + ((size_t)b * 256 + chunk * 32) * 4096;
    float acc = 0.f;
    for (int ci = 0; ci < 32; ++ci) {
        const float* xp = xb + (size_t)ci * 4096;
        const float* wp = ro_w + (chunk * 32 + ci) * 9;
#pragma unroll
        for (int dy = 0; dy < 3; ++dy) {
            int gy = y + dy - 1;
            if ((unsigned)gy >= 64u) continue;
#pragma unroll
            for (int dx = 0; dx < 3; ++dx) {
                int gx = xx + dx - 1;
                if ((unsigned)gx >= 64u) continue;
                acc = fmaf(wp[dy * 3 + dx], xp[gy * 64 + gx], acc);
            }
        }
    }
    atomicAdd(&YR[b * 4096 + px], acc);
}

// ---- readout per-object part (fp16 HWC states) + sigmoid
__global__ __launch_bounds__(256) void ro_obj(
    const ushort_t* __restrict__ S, const float* __restrict__ ro_w,
    const float* __restrict__ ro_b, const float* __restrict__ YR,
    float* __restrict__ out)
{
    int i = blockIdx.x * 256 + threadIdx.x;     // n(5)|px(12)
    int px = i & 4095, n = i >> 12;
    int b = n >> 3, y = px >> 6, xx = px & 63;
    float a[4];
    a[0] = YR[b * 4096 + px] + ro_b[0]; a[1] = 0.f; a[2] = 0.f; a[3] = 0.f;
    const ushort_t* sb = S + (size_t)n * 524288;
    const float* wb = ro_w + 256 * 9;
    for (int dy = 0; dy < 3; ++dy) {
        int gy = y + dy - 1;
        if ((unsigned)gy >= 64u) continue;
        for (int dx = 0; dx < 3; ++dx) {
            int gx = xx + dx - 1;
            if ((unsigned)gx >= 64u) continue;
            const ushort_t* sp = sb + (size_t)(gy * 64 + gx) * 128;
            const float* wp = wb + dy * 3 + dx;
#pragma unroll
            for (int c8 = 0; c8 < 16; ++c8) {
                uint4 v = *(const uint4*)(sp + c8 * 8);
                const ushort_t* vp = (const ushort_t*)&v;
#pragma unroll
                for (int k = 0; k < 8; ++k)
                    a[c8 & 3] = fmaf(h2f(vp[k]), wp[(c8 * 8 + k) * 9], a[c8 & 3]);
            }
        }
    }
    float acc = (a[0] + a[1]) + (a[2] + a[3]);
    out[i] = 1.f / (1.f + __expf(-acc));
}

extern "C" void kernel_launch(void* const* d_in, const int* in_sizes, int n_in,
                              void* d_out, int out_size, void* d_ws, size_t ws_size,
                              hipStream_t stream)
{
    const float* feats = (const float*)d_in[0];   // [4,256,64,64]
    const float* masks = (const float*)d_in[1];   // [4,8,64,64]
    const float* enc_w = (const float*)d_in[4];   // [128,257,3,3]
    const float* enc_b = (const float*)d_in[5];
    const float* gcn_w = (const float*)d_in[6];   // [128,256,3,3]
    const float* gcn_b = (const float*)d_in[7];
    const float* ro_w  = (const float*)d_in[8];   // [1,384,3,3]
    const float* ro_b  = (const float*)d_in[9];
    float* out = (float*)d_out;                   // [4,8,64,64]

    // workspace (ushort elements first, fp32 tail; all offsets 16B-aligned)
    ushort_t* WencF  = (ushort_t*)d_ws;           // 294912
    ushort_t* WgcnS  = WencF + 294912;            // 147456
    ushort_t* WgcnD  = WgcnS + 147456;            // 147456
    ushort_t* featsT = WgcnD + 147456;            // 4*4096*256
    ushort_t* S0     = featsT + 4194304;          // 32*4096*128
    ushort_t* S1     = S0 + 16777216;
    ushort_t* USum   = S1 + 16777216;             // 4*4096*128 fp16
    float*    U1     = (float*)(USum + 2097152);  // 4*4096*128 fp32
    float*    U2     = U1 + 2097152;              // 4*4096*128 fp32
    float*    YR     = U2 + 2097152;              // 4*4096 fp32

    dim3 blk(256);

    prep_weights<<<2304, blk, 0, stream>>>(enc_w, gcn_w, WencF, WgcnS, WgcnD);
    feats_to_hwc<<<dim3(64, 4, 4), blk, 0, stream>>>(feats, featsT);

    // encoder shared (cin=256) -> U1 fp32 (bias, no relu); per-object mask part -> S0
    conv_mfma<<<dim3(64, 4), blk, 0, stream>>>(featsT, 256, WencF, enc_b, nullptr, 0,
                                               nullptr, U1, 0);
    enc_obj<<<8192, blk, 0, stream>>>(masks, enc_w, U1, S0);

    // 2 message-passing steps: S0 -> S1 -> S0
    for (int step = 0; step < 2; ++step) {
        ushort_t* sin = step ? S1 : S0;
        ushort_t* sout = step ? S0 : S1;
        sum8_hwc<<<1024, blk, 0, stream>>>(sin, USum);
        conv_mfma<<<dim3(64, 4), blk, 0, stream>>>(USum, 128, WgcnS, gcn_b, nullptr, 0,
                                                   nullptr, U2, 0);
        conv_mfma<<<dim3(64, 32), blk, 0, stream>>>(sin, 128, WgcnD, nullptr, U2, 3,
                                                    sout, nullptr, 1);
    }

    // readout (final states in S0)
    hipMemsetAsync(YR, 0, 4 * 4096 * sizeof(float), stream);
    ro_shared<<<512, blk, 0, stream>>>(feats, ro_w, YR);
    ro_obj<<<512, blk, 0, stream>>>(S0, ro_w, ro_b, YR, out);
}

// Round 4
// 445.162 us; speedup vs baseline: 5.6614x; 1.1693x over previous
//
#include <hip/hip_runtime.h>
#include <math.h>

// B=4, O=8, C=256, HID=128, H=W=64, STEPS=2
// fp16 MFMA implicit-GEMM conv, fused dispatches.
//   enc:  relu(conv(feats,Wf) [ci-split partials] + conv(mask,Wm) + b)
//   gcn:  relu(conv(s_i, W1-W2) [raw] + conv(Sum, W2) + b)  -- one 36-image dispatch
//   ro :  sigmoid(conv(feats,Wa) + conv(s,Wb) + b)
// Activations fp16 HWC [img][px][ci]; weights pre-packed fp16 [tap][cout][cin].

typedef unsigned short ushort_t;
typedef _Float16 f16x8 __attribute__((ext_vector_type(8)));
typedef float f32x4 __attribute__((ext_vector_type(4)));

__device__ __forceinline__ ushort_t f2h(float f) {
    _Float16 h = (_Float16)f;
    return *(ushort_t*)&h;
}
__device__ __forceinline__ float h2f(ushort_t u) {
    _Float16 h = *(_Float16*)&u;
    return (float)h;
}

// ---- weight packing: WencF[9][128][256], WgcnS[9][128][128], WgcnD[9][128][128]
__global__ __launch_bounds__(256) void prep_weights(
    const float* __restrict__ enc_w, const float* __restrict__ gcn_w,
    ushort_t* __restrict__ WencF, ushort_t* __restrict__ WgcnS, ushort_t* __restrict__ WgcnD)
{
    int i = blockIdx.x * 256 + threadIdx.x;
    if (i < 294912) {                       // enc feats part: [t][co][ci<256]
        int t = i / 32768; int r = i & 32767; int co = r >> 8; int ci = r & 255;
        WencF[i] = f2h(enc_w[(co * 257 + ci) * 9 + t]);
    } else if (i < 442368) {                // gcn shared part W2
        int j = i - 294912; int t = j / 16384; int r = j & 16383; int co = r >> 7; int ci = r & 127;
        WgcnS[j] = f2h(gcn_w[(co * 256 + 128 + ci) * 9 + t]);
    } else if (i < 589824) {                // gcn diff W1-W2
        int j = i - 442368; int t = j / 16384; int r = j & 16383; int co = r >> 7; int ci = r & 127;
        WgcnD[j] = f2h(gcn_w[(co * 256 + ci) * 9 + t] - gcn_w[(co * 256 + 128 + ci) * 9 + t]);
    }
}

// ---- feats fp32 CHW -> fp16 HWC  [4][4096][256]
__global__ __launch_bounds__(256) void feats_to_hwc(const float* __restrict__ feats,
                                                    ushort_t* __restrict__ featsT)
{
    __shared__ float tile[64][65];
    int img = blockIdx.z, ct = blockIdx.y, pt = blockIdx.x;
    int t = threadIdx.x;
    int px_l = t & 63;
    const float* src = feats + ((size_t)img * 256 + ct * 64) * 4096 + pt * 64;
#pragma unroll
    for (int j = 0; j < 16; ++j) {
        int ci_l = (t >> 6) + j * 4;
        tile[px_l][ci_l] = src[(size_t)ci_l * 4096 + px_l];
    }
    __syncthreads();
    int px = t >> 2;
#pragma unroll
    for (int j = 0; j < 2; ++j) {
        int c8 = ((t & 3) + j * 4) * 8;
        uint4 v; ushort_t* pv = (ushort_t*)&v;
#pragma unroll
        for (int k = 0; k < 8; ++k) pv[k] = f2h(tile[px][c8 + k]);
        *(uint4*)(featsT + ((size_t)img * 4096 + pt * 64 + px) * 256 + ct * 64 + c8) = v;
    }
}

// ---- fused MFMA conv (raw outputs, no bias/relu here)
// grid: (64 rows, nA+nB images, zchunks). Each block: 64 px x 128 couts,
// cin=128 per block (2 LDS chunks of 64ci), A-frag prefetch pipelined.
// img < nA: x=xA[img], W=WA, out fp16 -> outA[img]
// img >= nA: x=xB[img-nA], W=WB, out fp32 -> outB[zc*nB + img-nA]
__global__ __launch_bounds__(256, 4) void conv_mfma(
    const ushort_t* __restrict__ xA, const ushort_t* __restrict__ WA,
    ushort_t* __restrict__ outA, int nA,
    const ushort_t* __restrict__ xB, const ushort_t* __restrict__ WB,
    float* __restrict__ outB, int nB, int cin_total)
{
    __shared__ uint4 raw[1782];               // 28512 B: xs[3][66][72] fp16 / outF[64][68] f32
    ushort_t* xs = (ushort_t*)raw;
    float* outF = (float*)raw;

    const int row = blockIdx.x, img = blockIdx.y, zc = blockIdx.z;
    const int ci0 = zc * 128;
    const int tid = threadIdx.x;
    const int w = tid >> 6, lane = tid & 63, lq = lane >> 4, lr = lane & 15;

    const bool isA = img < nA;
    const ushort_t* x = isA ? xA + (size_t)img * 4096 * cin_total
                            : xB + (size_t)(img - nA) * 4096 * cin_total;
    const ushort_t* W = isA ? WA : WB;

    f32x4 acc[2][4];
#pragma unroll
    for (int a = 0; a < 2; ++a)
#pragma unroll
        for (int p = 0; p < 4; ++p) acc[a][p] = (f32x4){0.f, 0.f, 0.f, 0.f};

    const int rowA0 = (w * 32 + lr) * cin_total;
    const int rowA1 = rowA0 + 16 * cin_total;

#pragma unroll
    for (int cc = 0; cc < 2; ++cc) {
        const int cib = ci0 + cc * 64;
        __syncthreads();
        for (int i = tid; i < 1584; i += 256) {
            int r = i / 528, rem = i - r * 528;
            int c = rem >> 3, s = rem & 7;
            int gy = row - 1 + r, gx = c - 1;
            uint4 v = make_uint4(0, 0, 0, 0);
            if ((unsigned)gy < 64u && (unsigned)gx < 64u)
                v = *(const uint4*)(x + (size_t)(gy * 64 + gx) * cin_total + cib + s * 8);
            *(uint4*)(xs + (r * 66 + c) * 72 + s * 8) = v;
        }
        __syncthreads();

        const ushort_t* Wk = W + cib + lq * 8;
        f16x8 n00 = *(const f16x8*)(Wk + rowA0);
        f16x8 n10 = *(const f16x8*)(Wk + rowA1);
        f16x8 n01 = *(const f16x8*)(Wk + rowA0 + 32);
        f16x8 n11 = *(const f16x8*)(Wk + rowA1 + 32);
#pragma unroll
        for (int t = 0; t < 9; ++t) {
            f16x8 a00 = n00, a10 = n10, a01 = n01, a11 = n11;
            if (t < 8) {
                const ushort_t* Wt = Wk + (size_t)(t + 1) * 128 * cin_total;
                n00 = *(const f16x8*)(Wt + rowA0);
                n10 = *(const f16x8*)(Wt + rowA1);
                n01 = *(const f16x8*)(Wt + rowA0 + 32);
                n11 = *(const f16x8*)(Wt + rowA1 + 32);
            }
            const int dy = t / 3, dx = t - dy * 3;
            const ushort_t* bb = xs + (dy * 66 + dx + lr) * 72 + lq * 8;
#pragma unroll
            for (int p = 0; p < 4; ++p) {
                f16x8 b0 = *(const f16x8*)(bb + p * 1152);        // p*16*72
                f16x8 b1 = *(const f16x8*)(bb + p * 1152 + 32);
                acc[0][p] = __builtin_amdgcn_mfma_f32_16x16x32_f16(a00, b0, acc[0][p], 0, 0, 0);
                acc[1][p] = __builtin_amdgcn_mfma_f32_16x16x32_f16(a10, b0, acc[1][p], 0, 0, 0);
                acc[0][p] = __builtin_amdgcn_mfma_f32_16x16x32_f16(a01, b1, acc[0][p], 0, 0, 0);
                acc[1][p] = __builtin_amdgcn_mfma_f32_16x16x32_f16(a11, b1, acc[1][p], 0, 0, 0);
            }
        }
    }

    // epilogue: LDS transpose -> coalesced raw stores (fp16 for A, fp32 for B)
    ushort_t* oA = isA ? outA + ((size_t)img * 4096 + row * 64) * 128 : (ushort_t*)0;
    float* oB = isA ? (float*)0
                    : outB + (((size_t)zc * nB + (img - nA)) * 4096 + row * 64) * 128;

#pragma unroll
    for (int h = 0; h < 2; ++h) {
        __syncthreads();
        if ((w >> 1) == h) {
            int wl = w & 1;
#pragma unroll
            for (int a = 0; a < 2; ++a)
#pragma unroll
                for (int p = 0; p < 4; ++p)
                    *(f32x4*)(outF + (p * 16 + lr) * 68 + wl * 32 + a * 16 + lq * 4) = acc[a][p];
        }
        __syncthreads();
        for (int i = tid; i < 512; i += 256) {
            int px = i >> 3, c8l = (i & 7) << 3;
            int c8 = h * 64 + c8l;
            f32x4 v0 = *(f32x4*)(outF + px * 68 + c8l);
            f32x4 v1 = *(f32x4*)(outF + px * 68 + c8l + 4);
            if (isA) {
                uint4 sv; ushort_t* sp = (ushort_t*)&sv;
#pragma unroll
                for (int k = 0; k < 4; ++k) { sp[k] = f2h(v0[k]); sp[k + 4] = f2h(v1[k]); }
                *(uint4*)(oA + px * 128 + c8) = sv;
            } else {
                *(f32x4*)(oB + px * 128 + c8) = v0;
                *(f32x4*)(oB + px * 128 + c8 + 4) = v1;
            }
        }
    }
}

// ---- gcn combine: S = relu(S_raw + U2[b] + gcn_b), USum = sum_o S  (fp32 math)
__global__ __launch_bounds__(256) void combine_sum(
    ushort_t* __restrict__ S, const float* __restrict__ U2,
    const float* __restrict__ gcn_b, ushort_t* __restrict__ USum)
{
    int i = blockIdx.x * 256 + threadIdx.x;   // b(2)|px(12)|c16(4)
    int c8 = (i & 15) << 3, px = (i >> 4) & 4095, b = i >> 16;
    const float* u = U2 + ((size_t)b * 4096 + px) * 128 + c8;
    float base[8];
#pragma unroll
    for (int k = 0; k < 8; ++k) base[k] = u[k] + gcn_b[c8 + k];
    float s[8] = {0, 0, 0, 0, 0, 0, 0, 0};
#pragma unroll
    for (int o = 0; o < 8; ++o) {
        ushort_t* p = S + ((size_t)(b * 8 + o) * 4096 + px) * 128 + c8;
        uint4 v = *(uint4*)p;
        ushort_t* vp = (ushort_t*)&v;
        uint4 sv; ushort_t* sp = (ushort_t*)&sv;
#pragma unroll
        for (int k = 0; k < 8; ++k) {
            float f = fmaxf(h2f(vp[k]) + base[k], 0.f);
            s[k] += f;
            sp[k] = f2h(f);
        }
        *(uint4*)p = sv;
    }
    uint4 sv; ushort_t* sp = (ushort_t*)&sv;
#pragma unroll
    for (int k = 0; k < 8; ++k) sp[k] = f2h(s[k]);
    *(uint4*)(USum + ((size_t)b * 4096 + px) * 128 + c8) = sv;
}

// ---- encoder per-object part + object-sum:
// S = relu(U1p0 + U1p1 + enc_b + conv3x3(mask_o, Wm)), USum = sum_o S
__global__ __launch_bounds__(256) void enc_obj_sum(
    const float* __restrict__ masks, const float* __restrict__ enc_w,
    const float* __restrict__ enc_b, const float* __restrict__ U1p,
    ushort_t* __restrict__ S, ushort_t* __restrict__ USum)
{
    int i = blockIdx.x * 256 + threadIdx.x;   // b(2)|px(12)|c16(4)
    int c8 = (i & 15) << 3, px = (i >> 4) & 4095, b = i >> 16;
    int y = px >> 6, xx = px & 63;
    const float* p0 = U1p + ((size_t)b * 4096 + px) * 128 + c8;
    const float* p1 = p0 + 2097152;           // second ci-half partial
    float base[8];
#pragma unroll
    for (int k = 0; k < 8; ++k) base[k] = p0[k] + p1[k] + enc_b[c8 + k];
    float wm[8][9];
#pragma unroll
    for (int k = 0; k < 8; ++k) {
        const float* wp = enc_w + (size_t)((c8 + k) * 257 + 256) * 9;
#pragma unroll
        for (int t = 0; t < 9; ++t) wm[k][t] = wp[t];
    }
    float s[8] = {0, 0, 0, 0, 0, 0, 0, 0};
#pragma unroll
    for (int o = 0; o < 8; ++o) {
        const float* m = masks + (size_t)(b * 8 + o) * 4096;
        float mt[9];
#pragma unroll
        for (int dy = 0; dy < 3; ++dy)
#pragma unroll
            for (int dx = 0; dx < 3; ++dx) {
                int gy = y + dy - 1, gx = xx + dx - 1;
                mt[dy * 3 + dx] =
                    ((unsigned)gy < 64u && (unsigned)gx < 64u) ? m[gy * 64 + gx] : 0.f;
            }
        uint4 sv; ushort_t* sp = (ushort_t*)&sv;
#pragma unroll
        for (int k = 0; k < 8; ++k) {
            float acc = base[k];
#pragma unroll
            for (int t = 0; t < 9; ++t) acc = fmaf(mt[t], wm[k][t], acc);
            acc = fmaxf(acc, 0.f);
            s[k] += acc;
            sp[k] = f2h(acc);
        }
        *(uint4*)(S + ((size_t)(b * 8 + o) * 4096 + px) * 128 + c8) = sv;
    }
    uint4 sv; ushort_t* sp = (ushort_t*)&sv;
#pragma unroll
    for (int k = 0; k < 8; ++k) sp[k] = f2h(s[k]);
    *(uint4*)(USum + ((size_t)b * 4096 + px) * 128 + c8) = sv;
}

// ---- readout shared part (fp32 feats CHW), split over ci-chunks + atomicAdd
__global__ __launch_bounds__(256) void ro_shared(const float* __restrict__ feats,
                                                 const float* __restrict__ ro_w,
                                                 float* __restrict__ YR)
{
    int i = blockIdx.x * 256 + threadIdx.x;   // b(2)|chunk(3)|px(12)
    int px = i & 4095, chunk = (i >> 12) & 7, b = i >> 15;
    int y = px >> 6, xx = px & 63;
    const float* xb = feats + ((size_t)b * 256 + chunk * 32) * 4096;
    float acc = 0.f;
    for (int ci = 0; ci < 32; ++ci) {
        const float* xp = xb + (size_t)ci * 4096;
        const float* wp = ro_w + (chunk * 32 + ci) * 9;
#pragma unroll
        for (int dy = 0; dy < 3; ++dy) {
            int gy = y + dy - 1;
            if ((unsigned)gy >= 64u) continue;
#pragma unroll
            for (int dx = 0; dx < 3; ++dx) {
                int gx = xx + dx - 1;
                if ((unsigned)gx >= 64u) continue;
                acc = fmaf(wp[dy * 3 + dx], xp[gy * 64 + gx], acc);
            }
        }
    }
    atomicAdd(&YR[b * 4096 + px], acc);
}

// ---- readout per-object part (fp16 HWC states) + sigmoid
__global__ __launch_bounds__(256) void ro_obj(
    const ushort_t* __restrict__ S, const float* __restrict__ ro_w,
    const float* __restrict__ ro_b, const float* __restrict__ YR,
    float* __restrict__ out)
{
    int i = blockIdx.x * 256 + threadIdx.x;   // n(5)|px(12)
    int px = i & 4095, n = i >> 12;
    int b = n >> 3, y = px >> 6, xx = px & 63;
    float a[4];
    a[0] = YR[b * 4096 + px] + ro_b[0]; a[1] = 0.f; a[2] = 0.f; a[3] = 0.f;
    const ushort_t* sb = S + (size_t)n * 524288;
    const float* wb = ro_w + 256 * 9;
    for (int dy = 0; dy < 3; ++dy) {
        int gy = y + dy - 1;
        if ((unsigned)gy >= 64u) continue;
        for (int dx = 0; dx < 3; ++dx) {
            int gx = xx + dx - 1;
            if ((unsigned)gx >= 64u) continue;
            const ushort_t* sp = sb + (size_t)(gy * 64 + gx) * 128;
            const float* wp = wb + dy * 3 + dx;
#pragma unroll
            for (int c8 = 0; c8 < 16; ++c8) {
                uint4 v = *(const uint4*)(sp + c8 * 8);
                const ushort_t* vp = (const ushort_t*)&v;
#pragma unroll
                for (int k = 0; k < 8; ++k)
                    a[c8 & 3] = fmaf(h2f(vp[k]), wp[(c8 * 8 + k) * 9], a[c8 & 3]);
            }
        }
    }
    float acc = (a[0] + a[1]) + (a[2] + a[3]);
    out[i] = 1.f / (1.f + __expf(-acc));
}

extern "C" void kernel_launch(void* const* d_in, const int* in_sizes, int n_in,
                              void* d_out, int out_size, void* d_ws, size_t ws_size,
                              hipStream_t stream)
{
    const float* feats = (const float*)d_in[0];   // [4,256,64,64]
    const float* masks = (const float*)d_in[1];   // [4,8,64,64]
    const float* enc_w = (const float*)d_in[4];   // [128,257,3,3]
    const float* enc_b = (const float*)d_in[5];
    const float* gcn_w = (const float*)d_in[6];   // [128,256,3,3]
    const float* gcn_b = (const float*)d_in[7];
    const float* ro_w  = (const float*)d_in[8];   // [1,384,3,3]
    const float* ro_b  = (const float*)d_in[9];
    float* out = (float*)d_out;                   // [4,8,64,64]

    // workspace: fp16 region then fp32 region (all 16B-aligned)
    ushort_t* WencF  = (ushort_t*)d_ws;           // 294912
    ushort_t* WgcnS  = WencF + 294912;            // 147456
    ushort_t* WgcnD  = WgcnS + 147456;            // 147456
    ushort_t* featsT = WgcnD + 147456;            // 4*4096*256
    ushort_t* Sa     = featsT + 4194304;          // 32*4096*128
    ushort_t* Sb     = Sa + 16777216;             // 32*4096*128
    ushort_t* USum   = Sb + 16777216;             // 4*4096*128
    float*    U1p    = (float*)(USum + 2097152);  // [2][4][4096][128] fp32
    float*    U2     = U1p + 4194304;             // [4][4096][128] fp32
    float*    YR     = U2 + 2097152;              // 4*4096 fp32

    dim3 blk(256);

    prep_weights<<<2304, blk, 0, stream>>>(enc_w, gcn_w, WencF, WgcnS, WgcnD);
    feats_to_hwc<<<dim3(64, 4, 4), blk, 0, stream>>>(feats, featsT);

    // encoder shared conv, ci-split into 2 partial dispatches-in-one (z=2)
    conv_mfma<<<dim3(64, 4, 2), blk, 0, stream>>>(
        nullptr, nullptr, nullptr, 0, featsT, WencF, U1p, 4, 256);
    enc_obj_sum<<<1024, blk, 0, stream>>>(masks, enc_w, enc_b, U1p, Sa, USum);

    // 2 message-passing steps, fused 36-image conv + combine
    conv_mfma<<<dim3(64, 36, 1), blk, 0, stream>>>(
        Sa, WgcnD, Sb, 32, USum, WgcnS, U2, 4, 128);
    combine_sum<<<1024, blk, 0, stream>>>(Sb, U2, gcn_b, USum);

    conv_mfma<<<dim3(64, 36, 1), blk, 0, stream>>>(
        Sb, WgcnD, Sa, 32, USum, WgcnS, U2, 4, 128);
    combine_sum<<<1024, blk, 0, stream>>>(Sa, U2, gcn_b, USum);

    // readout (final states in Sa)
    hipMemsetAsync(YR, 0, 4 * 4096 * sizeof(float), stream);
    ro_shared<<<512, blk, 0, stream>>>(feats, ro_w, YR);
    ro_obj<<<512, blk, 0, stream>>>(Sa, ro_w, ro_b, YR, out);
}